// Round 16
// baseline (943.247 us; speedup 1.0000x reference)
//
#include <hip/hip_runtime.h>
#include <hip/hip_bf16.h>

#define Bb 4
#define Cc 256
#define Nn 4096
#define NV 4160  // V row stride (kept from known-good proj)

typedef short s16x8 __attribute__((ext_vector_type(8)));
typedef float f32x4 __attribute__((ext_vector_type(4)));
typedef float f32x16 __attribute__((ext_vector_type(16)));

__device__ __forceinline__ unsigned short f2bf(float f) {
    unsigned u = __builtin_bit_cast(unsigned, f);
    u += 0x7FFFu + ((u >> 16) & 1u);
    return (unsigned short)(u >> 16);
}
__device__ __forceinline__ float bf2f(unsigned short u) {
    unsigned v = ((unsigned)u) << 16;
    return __builtin_bit_cast(float, v);
}
__device__ __forceinline__ unsigned pk2bf(float a, float b) {
    return (unsigned)f2bf(a) | ((unsigned)f2bf(b) << 16);
}

__device__ __forceinline__ f32x4 mfma16(s16x8 a, s16x8 b, f32x4 c) {
    return __builtin_amdgcn_mfma_f32_16x16x32_bf16(a, b, c, 0, 0, 0);
}
__device__ __forceinline__ f32x16 mfma32(s16x8 a, s16x8 b, f32x16 c) {
    return __builtin_amdgcn_mfma_f32_32x32x16_bf16(a, b, c, 0, 0, 0);
}

#if __has_builtin(__builtin_amdgcn_global_load_lds)
#define GL16(g, sdst)                                                              \
    __builtin_amdgcn_global_load_lds(                                              \
        (const __attribute__((address_space(1))) unsigned int*)(g),                \
        (__attribute__((address_space(3))) unsigned int*)(sdst), 16, 0, 0)
#else
#define GL16(g, sdst)                                                              \
    do {                                                                           \
        *(s16x8*)((char*)(sdst) + (threadIdx.x & 63) * 16) = *(const s16x8*)(g);   \
    } while (0)
#endif

// ---------------- prep: W fp32 -> bf16 ----------------
__global__ void prep_w(const float* __restrict__ Wq, const float* __restrict__ Wk,
                       const float* __restrict__ Wv, unsigned short* __restrict__ Wbf) {
    int idx = (blockIdx.x * 256 + threadIdx.x) * 8;  // < 3*65536
    int mat = idx >> 16;
    int off = idx & 65535;
    const float* src = (mat == 0) ? Wq : ((mat == 1) ? Wk : Wv);
    float4 a = *(const float4*)(src + off);
    float4 b = *(const float4*)(src + off + 4);
    s16x8 o;
    o[0] = (short)f2bf(a.x); o[1] = (short)f2bf(a.y);
    o[2] = (short)f2bf(a.z); o[3] = (short)f2bf(a.w);
    o[4] = (short)f2bf(b.x); o[5] = (short)f2bf(b.y);
    o[6] = (short)f2bf(b.z); o[7] = (short)f2bf(b.w);
    *(s16x8*)(Wbf + idx) = o;
}

// ---------------- transpose: x[b][c][n] fp32 -> xT[b][n][c] bf16 ----------------
__global__ void transpose_x(const float* __restrict__ x, unsigned short* __restrict__ xT) {
    int b = blockIdx.z, c0 = blockIdx.y * 64, n0 = blockIdx.x * 64;
    __shared__ float tile[64][65];
    int t = threadIdx.x;
    int r = t >> 2, q = t & 3;
    const float* src = x + ((size_t)(b * Cc + c0 + r)) * Nn + n0 + q * 16;
#pragma unroll
    for (int j = 0; j < 4; j++) {
        float4 v4 = *(const float4*)(src + j * 4);
        tile[r][q * 16 + j * 4 + 0] = v4.x;
        tile[r][q * 16 + j * 4 + 1] = v4.y;
        tile[r][q * 16 + j * 4 + 2] = v4.z;
        tile[r][q * 16 + j * 4 + 3] = v4.w;
    }
    __syncthreads();
    unsigned short* dst = xT + ((size_t)b * Nn + n0 + r) * Cc + c0 + q * 16;
    s16x8 o0, o1;
#pragma unroll
    for (int j = 0; j < 8; j++) o0[j] = (short)f2bf(tile[q * 16 + j][r]);
#pragma unroll
    for (int j = 0; j < 8; j++) o1[j] = (short)f2bf(tile[q * 16 + 8 + j][r]);
    *(s16x8*)dst = o0;
    *(s16x8*)(dst + 8) = o1;
}

// ---------------- projections ----------------
__global__ void proj(const unsigned short* __restrict__ xT, const unsigned short* __restrict__ Wbf,
                     const float* __restrict__ bq, const float* __restrict__ bk,
                     const float* __restrict__ bv,
                     unsigned short* __restrict__ qT, unsigned short* __restrict__ kT,
                     unsigned short* __restrict__ vO) {
    int nt0 = blockIdx.x * 64;
    int mat = blockIdx.y;
    int b   = blockIdx.z;
    int t = threadIdx.x, w = t >> 6, l = t & 63;
    int lr = l & 15, lg = l >> 4;
    const unsigned short* Wm  = Wbf + mat * (Cc * Cc);
    const float* bias = (mat == 0) ? bq : ((mat == 1) ? bk : bv);
    const unsigned short* xTb = xT + (size_t)b * Nn * Cc;

    if (mat < 2) {
        unsigned short* out = ((mat == 0) ? qT : kT) + (size_t)b * Nn * Cc;
        int nrow = nt0 + w * 16;
        s16x8 af[8];
#pragma unroll
        for (int kk = 0; kk < 8; kk++)
            af[kk] = *(const s16x8*)(xTb + (nrow + lr) * Cc + kk * 32 + lg * 8);
        for (int ct = 0; ct < 16; ct++) {
            f32x4 acca = {0, 0, 0, 0}, accb = {0, 0, 0, 0};
#pragma unroll
            for (int kk = 0; kk < 8; kk += 2) {
                s16x8 bfa = *(const s16x8*)(Wm + (ct * 16 + lr) * Cc + kk * 32 + lg * 8);
                s16x8 bfb = *(const s16x8*)(Wm + (ct * 16 + lr) * Cc + (kk + 1) * 32 + lg * 8);
                acca = mfma16(af[kk], bfa, acca);
                accb = mfma16(af[kk + 1], bfb, accb);
            }
            f32x4 acc = acca + accb;
            float bb = bias[ct * 16 + lr];
#pragma unroll
            for (int r = 0; r < 4; r++)
                out[(nrow + lg * 4 + r) * Cc + ct * 16 + lr] = f2bf(acc[r] + bb);
        }
    } else {
        unsigned short* out = vO + (size_t)b * Cc * NV;
        for (int mt = 0; mt < 4; mt++) {
            int crow = (w * 4 + mt) * 16;
            s16x8 af[8];
#pragma unroll
            for (int kk = 0; kk < 8; kk++)
                af[kk] = *(const s16x8*)(Wm + (crow + lr) * Cc + kk * 32 + lg * 8);
#pragma unroll
            for (int nt = 0; nt < 4; nt++) {
                f32x4 acca = {0, 0, 0, 0}, accb = {0, 0, 0, 0};
#pragma unroll
                for (int kk = 0; kk < 8; kk += 2) {
                    s16x8 bfa = *(const s16x8*)(xTb + (nt0 + nt * 16 + lr) * Cc + kk * 32 + lg * 8);
                    s16x8 bfb = *(const s16x8*)(xTb + (nt0 + nt * 16 + lr) * Cc + (kk + 1) * 32 + lg * 8);
                    acca = mfma16(af[kk], bfa, acca);
                    accb = mfma16(af[kk + 1], bfb, accb);
                }
                f32x4 acc = acca + accb;
#pragma unroll
                for (int r = 0; r < 4; r++) {
                    float bb = bias[crow + lg * 4 + r];
                    out[(size_t)(crow + lg * 4 + r) * NV + nt0 + nt * 16 + lr] = f2bf(acc[r] + bb);
                }
            }
        }
    }
}

// ---------------- fused flash attention, 32x32 MFMA, 4 waves/SIMD ----------
// 512 blocks x 512 thr (8 waves x 32 i-rows = 256 rows/block), S=8.
// 2 independent blocks/CU x 8 waves = 16 waves/CU = 4 waves/SIMD (the axis
// R15 left unexplored: per-wave VGPR=128 exactly permits it).
// XCD map: xcd=id&7, 4 combos/XCD (0.25MB K + 0.25MB V each = 2MB resident),
// 16 lockstep blocks/combo. Per-wave code identical to R15 (verified):
// QK^T mfma32(K,Q) -> E[j][i]; in-register softmax + bf16 pack +
// shfl_xor(32) remap -> B-frag; PV mfma32(V,P) -> O[c][i].
// Partials bf16 [c][n]-major (R15-proven clean), 8-way merge.
__global__ void __launch_bounds__(512, 4)
attn(const unsigned short* __restrict__ qT, const unsigned short* __restrict__ kT,
     const unsigned short* __restrict__ vv,
     unsigned short* __restrict__ OPT, float* __restrict__ lp) {
    int id = blockIdx.x;
    int xcd = id & 7, k = id >> 3;             // k 0..63
    int combo = xcd * 4 + (k & 3);             // 0..31 = b*8 + s
    int b = combo >> 3, s = combo & 7;
    int iblk = k >> 2;                         // 0..15
    int t = threadIdx.x, w = t >> 6, l = t & 63;
    int la = l & 31, lh = l >> 5;              // row/col id within 32, k-half
    int i0 = iblk * 256 + w * 32;

    __shared__ char Ks[2][16384];        // K tile dbuf: 32 rows x 512B (swz (row&7)<<4)
    __shared__ char Vs[2][16384];        // V tile dbuf: 256 rows x 64B (swz ((row>>1)&3)<<4)

    const unsigned short* qb = qT + ((size_t)b * Nn + i0) * Cc;
    const char* kbase = (const char*)(kT + ((size_t)b * Nn + s * 512) * Cc);
    const char* vbase = (const char*)(vv + (size_t)b * Cc * NV + s * 512);

    // Q as B-operand fragments: col i = la, k c = kk*16 + lh*8 + e
    s16x8 qf[16];
#pragma unroll
    for (int kk = 0; kk < 16; kk++)
        qf[kk] = *(const s16x8*)(qb + la * Cc + kk * 16 + lh * 8);

    f32x16 O[8];  // O[ct]: c = ct*32 + (reg&3)+8*(reg>>2)+4*lh, i = i0+la
#pragma unroll
    for (int ct = 0; ct < 8; ct++)
#pragma unroll
        for (int r = 0; r < 16; r++) O[ct][r] = 0.f;
    float lsum = 0.f;
    const float L2E = 1.44269504088896340736f;

// stage 16KB K tile (32 rows x 512B); 16 chunks of 1KB; wave w covers w*2, w*2+1
#define STAGEK(bufi, jt)                                                        \
    {                                                                           \
        const char* ksl_ = kbase + (size_t)(jt) * 16384;                        \
        _Pragma("unroll") for (int i_ = 0; i_ < 2; i_++) {                      \
            int chunk_ = w * 2 + i_;                                            \
            int L_ = chunk_ * 1024 + l * 16;                                    \
            int row_ = L_ >> 9;                                                 \
            GL16(ksl_ + (L_ ^ ((row_ & 7) << 4)), &Ks[bufi][chunk_ * 1024]);    \
        }                                                                       \
    }

// stage 16KB V tile (256 rows x 64B); 16 chunks; wave w covers w*2, w*2+1
#define STAGEV(bufi, jt)                                                        \
    {                                                                           \
        _Pragma("unroll") for (int i_ = 0; i_ < 2; i_++) {                      \
            int chunk_ = w * 2 + i_;                                            \
            int row_ = chunk_ * 16 + (l >> 2);                                  \
            int colb_ = ((l & 3) * 16) ^ (((l >> 3) & 3) << 4);                 \
            GL16(vbase + (size_t)row_ * (NV * 2) + (size_t)(jt) * 64 + colb_,   \
                 &Vs[bufi][chunk_ * 1024]);                                     \
        }                                                                       \
    }

    STAGEK(0, 0);
    STAGEV(0, 0);
    asm volatile("s_waitcnt vmcnt(0)" ::: "memory");
    __syncthreads();
    int buf = 0;

    for (int jt = 0; jt < 16; jt++) {
        if (jt < 15) {
            STAGEK(buf ^ 1, jt + 1);
            STAGEV(buf ^ 1, jt + 1);
        }
        // ---- QK^T: E[j][i]; lane: i = la, j = (reg&3)+8*(reg>>2)+4*lh ----
        const char* ksb = Ks[buf];
        f32x16 E;
#pragma unroll
        for (int r = 0; r < 16; r++) E[r] = 0.f;
        __builtin_amdgcn_s_setprio(1);
#pragma unroll
        for (int kk = 0; kk < 16; kk++) {
            s16x8 kf = *(const s16x8*)(ksb + la * 512 +
                                       ((kk * 32 + lh * 16) ^ ((l & 7) << 4)));
            E = mfma32(kf, qf[kk], E);
        }
        __builtin_amdgcn_s_setprio(0);
        // ---- shift-free softmax in place; lane sums its 16 j's ----
#pragma unroll
        for (int r = 0; r < 16; r++) {
            float pv = exp2f(E[r] * L2E);
            E[r] = pv;
            lsum += pv;
        }
        // ---- pack pairs to bf16 and exchange halves (j-remap to B-frag) ----
        unsigned pk0 = pk2bf(E[0], E[1]),   pk1 = pk2bf(E[2], E[3]);
        unsigned pk2 = pk2bf(E[4], E[5]),   pk3 = pk2bf(E[6], E[7]);
        unsigned pk4 = pk2bf(E[8], E[9]),   pk5 = pk2bf(E[10], E[11]);
        unsigned pk6 = pk2bf(E[12], E[13]), pk7 = pk2bf(E[14], E[15]);
        unsigned x0 = (unsigned)__shfl_xor((int)pk0, 32);
        unsigned x1 = (unsigned)__shfl_xor((int)pk1, 32);
        unsigned x2 = (unsigned)__shfl_xor((int)pk2, 32);
        unsigned x3 = (unsigned)__shfl_xor((int)pk3, 32);
        unsigned x4 = (unsigned)__shfl_xor((int)pk4, 32);
        unsigned x5 = (unsigned)__shfl_xor((int)pk5, 32);
        unsigned x6 = (unsigned)__shfl_xor((int)pk6, 32);
        unsigned x7 = (unsigned)__shfl_xor((int)pk7, 32);
        bool h1 = (lh == 1);
        uint4 w0, w1;
        w0.x = h1 ? x2 : pk0;  w0.y = h1 ? x3 : pk1;   // jc0: j = lh*8 + 0..7
        w0.z = h1 ? pk2 : x0;  w0.w = h1 ? pk3 : x1;
        w1.x = h1 ? x6 : pk4;  w1.y = h1 ? x7 : pk5;   // jc1: j = 16 + lh*8 + 0..7
        w1.z = h1 ? pk6 : x4;  w1.w = h1 ? pk7 : x5;
        s16x8 pf0 = __builtin_bit_cast(s16x8, w0);
        s16x8 pf1 = __builtin_bit_cast(s16x8, w1);
        // ---- PV: O[c][i] += V[c][j] P[j][i] ----
        const char* vsb = Vs[buf];
        int vsw = ((l >> 1) & 3) << 4;
        __builtin_amdgcn_s_setprio(1);
#pragma unroll
        for (int ct = 0; ct < 8; ct++) {
            s16x8 va = *(const s16x8*)(vsb + (ct * 32 + la) * 64 +
                                       ((lh * 16) ^ vsw));
            O[ct] = mfma32(va, pf0, O[ct]);
            s16x8 vb = *(const s16x8*)(vsb + (ct * 32 + la) * 64 +
                                       ((32 + lh * 16) ^ vsw));
            O[ct] = mfma32(vb, pf1, O[ct]);
        }
        __builtin_amdgcn_s_setprio(0);
        asm volatile("s_waitcnt vmcnt(0)" ::: "memory");
        __syncthreads();
        buf ^= 1;
    }

    // ---- l: lane has half the j's for row i=la; partner has the rest ----
    lsum += __shfl_xor(lsum, 32);
    if (l < 32)
        lp[(size_t)combo * Nn + i0 + l] = lsum;
    // ---- bf16 partials, [c][n]-major: 32 lanes contiguous in n ----
    unsigned short* ob = OPT + (size_t)combo * Cc * Nn;
#pragma unroll
    for (int ct = 0; ct < 8; ct++) {
#pragma unroll
        for (int g = 0; g < 4; g++) {
#pragma unroll
            for (int r = 0; r < 4; r++) {
                int c = ct * 32 + 8 * g + 4 * lh + r;
                ob[(size_t)c * Nn + i0 + la] = f2bf(O[ct][4 * g + r]);
            }
        }
    }
#undef STAGEK
#undef STAGEV
}

// ---------------- merge 8 bf16 partials + epilogue (transpose-free) ----------
// out[b][c][n] = gamma * (sum_s OPT[b*8+s])[c][n] / (sum_s l)[n] + x[b][c][n]
__global__ void __launch_bounds__(256)
merge(const unsigned short* __restrict__ OPT, const float* __restrict__ lp,
      const float* __restrict__ x, const float* __restrict__ gamma,
      float* __restrict__ out) {
    int b = blockIdx.z, c0 = blockIdx.y * 64, n0 = blockIdx.x * 64;
    __shared__ float linv[64];
    int t = threadIdx.x;
    if (t < 64) {
        float sum = 0.f;
#pragma unroll
        for (int si = 0; si < 8; si++)
            sum += lp[(size_t)(b * 8 + si) * Nn + n0 + t];
        linv[t] = 1.0f / sum;
    }
    __syncthreads();
    float g = gamma[0];
    int r = t >> 2, q = t & 3;
    int c = c0 + r;
    float acc[16];
#pragma unroll
    for (int j = 0; j < 16; j++) acc[j] = 0.f;
#pragma unroll
    for (int si = 0; si < 8; si++) {
        const unsigned short* p = OPT + ((size_t)((b * 8 + si) * Cc + c)) * Nn + n0 + q * 16;
        s16x8 v0 = *(const s16x8*)p;
        s16x8 v1 = *(const s16x8*)(p + 8);
#pragma unroll
        for (int j = 0; j < 8; j++) {
            acc[j] += bf2f((unsigned short)v0[j]);
            acc[8 + j] += bf2f((unsigned short)v1[j]);
        }
    }
    const float* xp = x + ((size_t)b * Cc + c) * Nn + n0 + q * 16;
    float* op = out + ((size_t)b * Cc + c) * Nn + n0 + q * 16;
#pragma unroll
    for (int j4 = 0; j4 < 4; j4++) {
        float4 xv = *(const float4*)(xp + j4 * 4);
        float4 o4;
        o4.x = g * acc[j4 * 4 + 0] * linv[q * 16 + j4 * 4 + 0] + xv.x;
        o4.y = g * acc[j4 * 4 + 1] * linv[q * 16 + j4 * 4 + 1] + xv.y;
        o4.z = g * acc[j4 * 4 + 2] * linv[q * 16 + j4 * 4 + 2] + xv.z;
        o4.w = g * acc[j4 * 4 + 3] * linv[q * 16 + j4 * 4 + 3] + xv.w;
        *(float4*)(op + j4 * 4) = o4;
    }
}

extern "C" void kernel_launch(void* const* d_in, const int* in_sizes, int n_in,
                              void* d_out, int out_size, void* d_ws, size_t ws_size,
                              hipStream_t stream) {
    (void)in_sizes; (void)n_in; (void)out_size; (void)ws_size;
    const float* x     = (const float*)d_in[0];
    const float* Wq    = (const float*)d_in[1];
    const float* bq    = (const float*)d_in[2];
    const float* Wk    = (const float*)d_in[3];
    const float* bk    = (const float*)d_in[4];
    const float* Wv    = (const float*)d_in[5];
    const float* bv    = (const float*)d_in[6];
    const float* gamma = (const float*)d_in[7];
    float* out = (float*)d_out;

    const size_t XTN = (size_t)Bb * Nn * Cc;   // 4,194,304 elements
    const size_t VSZ = (size_t)Bb * Cc * NV;   // padded V
    unsigned short* xT  = (unsigned short*)d_ws;
    unsigned short* Wbf = xT + XTN;
    unsigned short* qT  = Wbf + 3 * Cc * Cc;
    unsigned short* kT  = qT + XTN;
    unsigned short* vv  = kT + XTN;
    unsigned short* OPT = vv + VSZ;                  // 32 slices bf16 = 64MB
    float*          lp  = (float*)(OPT + (size_t)32 * Nn * Cc);

    hipLaunchKernelGGL(prep_w, dim3(96), dim3(256), 0, stream, Wq, Wk, Wv, Wbf);
    hipLaunchKernelGGL(transpose_x, dim3(Nn / 64, Cc / 64, Bb), dim3(256), 0, stream, x, xT);
    hipLaunchKernelGGL(proj, dim3(Nn / 64, 3, Bb), dim3(256), 0, stream,
                       xT, Wbf, bq, bk, bv, qT, kT, vv);
    hipLaunchKernelGGL(attn, dim3(512), dim3(512), 0, stream,
                       qT, kT, vv, OPT, lp);
    hipLaunchKernelGGL(merge, dim3(Nn / 64, Cc / 64, Bb), dim3(256), 0, stream,
                       OPT, lp, x, gamma, out);
}

// Round 17
// 202.986 us; speedup vs baseline: 4.6469x; 4.6469x over previous
//
#include <hip/hip_runtime.h>
#include <hip/hip_bf16.h>

#define Bb 4
#define Cc 256
#define Nn 4096
#define NV 4160  // V row stride (padded; addresses computed explicitly)

typedef short s16x8 __attribute__((ext_vector_type(8)));
typedef float f32x4 __attribute__((ext_vector_type(4)));

__device__ __forceinline__ unsigned short f2bf(float f) {
    unsigned u = __builtin_bit_cast(unsigned, f);
    u += 0x7FFFu + ((u >> 16) & 1u);
    return (unsigned short)(u >> 16);
}

__device__ __forceinline__ unsigned pk2bf(float a, float b) {
    return (unsigned)f2bf(a) | ((unsigned)f2bf(b) << 16);
}

__device__ __forceinline__ f32x4 mfma16(s16x8 a, s16x8 b, f32x4 c) {
    return __builtin_amdgcn_mfma_f32_16x16x32_bf16(a, b, c, 0, 0, 0);
}

#if __has_builtin(__builtin_amdgcn_global_load_lds)
#define GL16(g, sdst)                                                              \
    __builtin_amdgcn_global_load_lds(                                              \
        (const __attribute__((address_space(1))) unsigned int*)(g),                \
        (__attribute__((address_space(3))) unsigned int*)(sdst), 16, 0, 0)
#else
#define GL16(g, sdst)                                                              \
    do {                                                                           \
        *(s16x8*)((char*)(sdst) + (threadIdx.x & 63) * 16) = *(const s16x8*)(g);   \
    } while (0)
#endif

// ---------------- prep: W fp32 -> bf16 ----------------
__global__ void prep_w(const float* __restrict__ Wq, const float* __restrict__ Wk,
                       const float* __restrict__ Wv, unsigned short* __restrict__ Wbf) {
    int idx = (blockIdx.x * 256 + threadIdx.x) * 8;  // < 3*65536
    int mat = idx >> 16;
    int off = idx & 65535;
    const float* src = (mat == 0) ? Wq : ((mat == 1) ? Wk : Wv);
    float4 a = *(const float4*)(src + off);
    float4 b = *(const float4*)(src + off + 4);
    s16x8 o;
    o[0] = (short)f2bf(a.x); o[1] = (short)f2bf(a.y);
    o[2] = (short)f2bf(a.z); o[3] = (short)f2bf(a.w);
    o[4] = (short)f2bf(b.x); o[5] = (short)f2bf(b.y);
    o[6] = (short)f2bf(b.z); o[7] = (short)f2bf(b.w);
    *(s16x8*)(Wbf + idx) = o;
}

// ---------------- transpose: x[b][c][n] fp32 -> xT[b][n][c] bf16 ----------------
__global__ void transpose_x(const float* __restrict__ x, unsigned short* __restrict__ xT) {
    int b = blockIdx.z, c0 = blockIdx.y * 64, n0 = blockIdx.x * 64;
    __shared__ float tile[64][65];
    int t = threadIdx.x;
    int r = t >> 2, q = t & 3;
    const float* src = x + ((size_t)(b * Cc + c0 + r)) * Nn + n0 + q * 16;
#pragma unroll
    for (int j = 0; j < 4; j++) {
        float4 v4 = *(const float4*)(src + j * 4);
        tile[r][q * 16 + j * 4 + 0] = v4.x;
        tile[r][q * 16 + j * 4 + 1] = v4.y;
        tile[r][q * 16 + j * 4 + 2] = v4.z;
        tile[r][q * 16 + j * 4 + 3] = v4.w;
    }
    __syncthreads();
    unsigned short* dst = xT + ((size_t)b * Nn + n0 + r) * Cc + c0 + q * 16;
    s16x8 o0, o1;
#pragma unroll
    for (int j = 0; j < 8; j++) o0[j] = (short)f2bf(tile[q * 16 + j][r]);
#pragma unroll
    for (int j = 0; j < 8; j++) o1[j] = (short)f2bf(tile[q * 16 + 8 + j][r]);
    *(s16x8*)dst = o0;
    *(s16x8*)(dst + 8) = o1;
}

// ---------------- projections ----------------
__global__ void proj(const unsigned short* __restrict__ xT, const unsigned short* __restrict__ Wbf,
                     const float* __restrict__ bq, const float* __restrict__ bk,
                     const float* __restrict__ bv,
                     unsigned short* __restrict__ qT, unsigned short* __restrict__ kT,
                     unsigned short* __restrict__ vO) {
    int nt0 = blockIdx.x * 64;
    int mat = blockIdx.y;
    int b   = blockIdx.z;
    int t = threadIdx.x, w = t >> 6, l = t & 63;
    int lr = l & 15, lg = l >> 4;
    const unsigned short* Wm  = Wbf + mat * (Cc * Cc);
    const float* bias = (mat == 0) ? bq : ((mat == 1) ? bk : bv);
    const unsigned short* xTb = xT + (size_t)b * Nn * Cc;

    if (mat < 2) {
        unsigned short* out = ((mat == 0) ? qT : kT) + (size_t)b * Nn * Cc;
        int nrow = nt0 + w * 16;
        s16x8 af[8];
#pragma unroll
        for (int kk = 0; kk < 8; kk++)
            af[kk] = *(const s16x8*)(xTb + (nrow + lr) * Cc + kk * 32 + lg * 8);
        for (int ct = 0; ct < 16; ct++) {
            f32x4 acca = {0, 0, 0, 0}, accb = {0, 0, 0, 0};
#pragma unroll
            for (int kk = 0; kk < 8; kk += 2) {
                s16x8 bfa = *(const s16x8*)(Wm + (ct * 16 + lr) * Cc + kk * 32 + lg * 8);
                s16x8 bfb = *(const s16x8*)(Wm + (ct * 16 + lr) * Cc + (kk + 1) * 32 + lg * 8);
                acca = mfma16(af[kk], bfa, acca);
                accb = mfma16(af[kk + 1], bfb, accb);
            }
            f32x4 acc = acca + accb;
            float bb = bias[ct * 16 + lr];
#pragma unroll
            for (int r = 0; r < 4; r++)
                out[(nrow + lg * 4 + r) * Cc + ct * 16 + lr] = f2bf(acc[r] + bb);
        }
    } else {
        unsigned short* out = vO + (size_t)b * Cc * NV;
        for (int mt = 0; mt < 4; mt++) {
            int crow = (w * 4 + mt) * 16;
            s16x8 af[8];
#pragma unroll
            for (int kk = 0; kk < 8; kk++)
                af[kk] = *(const s16x8*)(Wm + (crow + lr) * Cc + kk * 32 + lg * 8);
#pragma unroll
            for (int nt = 0; nt < 4; nt++) {
                f32x4 acca = {0, 0, 0, 0}, accb = {0, 0, 0, 0};
#pragma unroll
                for (int kk = 0; kk < 8; kk += 2) {
                    s16x8 bfa = *(const s16x8*)(xTb + (nt0 + nt * 16 + lr) * Cc + kk * 32 + lg * 8);
                    s16x8 bfb = *(const s16x8*)(xTb + (nt0 + nt * 16 + lr) * Cc + (kk + 1) * 32 + lg * 8);
                    acca = mfma16(af[kk], bfa, acca);
                    accb = mfma16(af[kk + 1], bfb, accb);
                }
                f32x4 acc = acca + accb;
#pragma unroll
                for (int r = 0; r < 4; r++) {
                    float bb = bias[crow + lg * 4 + r];
                    out[(size_t)(crow + lg * 4 + r) * NV + nt0 + nt * 16 + lr] = f2bf(acc[r] + bb);
                }
            }
        }
    }
}

// ---------------- fused flash attention: 3 independent blocks/CU ----------
// R14 per-wave structure (in-reg P via swapped MFMA; 16 rows/wave) with two
// diets to fit 3 blocks/CU (the untested lever; per-SIMD reg pool = 512,
// so 3 waves need <=170 regs; LDS <=53KB):
//  - LDS 48KB: K dbuf 32K + V SINGLE-buffered 16K. V(t+1) staged between
//    barrier1 (Vs consumers done) and barrier2; the exposed window is
//    covered by the other two blocks' compute (independent chains).
//  - regs ~164: PV consumes V in 4 batches of 4 fragments (vfr 64->16).
// Geometry/cache map = R11 (512 blocks, 4 waves x 16 rows, S=2 combo/XCD).
__global__ void __launch_bounds__(256, 3)
attn(const unsigned short* __restrict__ qT, const unsigned short* __restrict__ kT,
     const unsigned short* __restrict__ vv,
     float* __restrict__ OPT, float* __restrict__ lp) {
    int id = blockIdx.x;
    int bs = id & 7, b = bs >> 1, s = bs & 1, iblk = id >> 3;  // iblk 0..63
    int t = threadIdx.x, w = t >> 6, l = t & 63;
    int lr = l & 15, lg = l >> 4;
    int i0 = iblk * 64 + w * 16;

    __shared__ char Ks[2][16384];   // K tile dbuf: 32 rows x 512B (swz (row&7)<<4)
    __shared__ char Vs[16384];      // V tile single: 256 rows x 64B (swz ((row>>1)&3)<<4)

    const unsigned short* qb = qT + ((size_t)b * Nn + i0) * Cc;
    const char* kbase = (const char*)(kT + ((size_t)b * Nn + s * 2048) * Cc);
    const char* vbase = (const char*)(vv + (size_t)b * Cc * NV + s * 2048);

    s16x8 qf[8];
#pragma unroll
    for (int kk = 0; kk < 8; kk++)
        qf[kk] = *(const s16x8*)(qb + lr * Cc + kk * 32 + lg * 8);

    f32x4 O[16];  // O[ct][r] = O[c = ct*16 + lg*4 + r][i = i0 + lr]
#pragma unroll
    for (int ct = 0; ct < 16; ct++) O[ct] = {0, 0, 0, 0};
    float lsum = 0.f;
    const float L2E = 1.44269504088896340736f;

#define STAGEK(bufi, jt)                                                        \
    {                                                                           \
        const char* ksl_ = kbase + (size_t)(jt) * 16384;                        \
        _Pragma("unroll") for (int i_ = 0; i_ < 4; i_++) {                      \
            int chunk_ = w * 4 + i_;                                            \
            int L_ = chunk_ * 1024 + l * 16;                                    \
            int row_ = L_ >> 9;                                                 \
            GL16(ksl_ + (L_ ^ ((row_ & 7) << 4)), &Ks[bufi][chunk_ * 1024]);    \
        }                                                                       \
    }

#define STAGEV(jt)                                                              \
    {                                                                           \
        _Pragma("unroll") for (int i_ = 0; i_ < 4; i_++) {                      \
            int chunk_ = w * 4 + i_;                                            \
            int row_ = chunk_ * 16 + (l >> 2);                                  \
            int colb_ = ((l & 3) * 16) ^ (((l >> 3) & 3) << 4);                 \
            GL16(vbase + (size_t)row_ * (NV * 2) + (size_t)(jt) * 64 + colb_,   \
                 &Vs[chunk_ * 1024]);                                           \
        }                                                                       \
    }

    STAGEK(0, 0);
    STAGEV(0);
    asm volatile("s_waitcnt vmcnt(0)" ::: "memory");
    __syncthreads();
    int buf = 0;

    for (int jt = 0; jt < 64; jt++) {
        // ---- prefetch next K tile into the other K buffer (DMA) ----
        if (jt < 63) STAGEK(buf ^ 1, jt + 1);
        // ---- QK^T swapped: E^T[j][i]; lane (lr,lg) reg r: j=lg*4+r, i=lr ----
        const char* ksb = Ks[buf];
        f32x4 E0 = {0, 0, 0, 0}, E1 = {0, 0, 0, 0};
        __builtin_amdgcn_s_setprio(1);
#pragma unroll
        for (int kk = 0; kk < 8; kk++) {
            int cb = (kk * 64 + lg * 16) ^ ((lr & 7) << 4);
            s16x8 k0 = *(const s16x8*)(ksb + lr * 512 + cb);
            s16x8 k1 = *(const s16x8*)(ksb + (16 + lr) * 512 + cb);
            E0 = mfma16(k0, qf[kk], E0);   // j = 0..15 of tile
            E1 = mfma16(k1, qf[kk], E1);   // j = 16..31 of tile
        }
        __builtin_amdgcn_s_setprio(0);
        // ---- shift-free softmax; each lane: 8 p's, all for row i = lr ----
        float p0[4], p1[4];
#pragma unroll
        for (int r = 0; r < 4; r++) {
            p0[r] = exp2f(E0[r] * L2E);
            p1[r] = exp2f(E1[r] * L2E);
            lsum += p0[r] + p1[r];
        }
        // ---- register remap to B-frag[k=j][col=i] (no LDS, no drain) ----
        unsigned h0a = pk2bf(p0[0], p0[1]), h0b = pk2bf(p0[2], p0[3]);
        unsigned h1a = pk2bf(p1[0], p1[1]), h1b = pk2bf(p1[2], p1[3]);
        int sA = lr + ((lg & 1) << 5);  // lr + 32*(lg&1)
        int sB = sA + 16;
        unsigned a0 = (unsigned)__shfl((int)h0a, sA);
        unsigned b0 = (unsigned)__shfl((int)h1a, sA);
        unsigned a1 = (unsigned)__shfl((int)h0b, sA);
        unsigned b1 = (unsigned)__shfl((int)h1b, sA);
        unsigned a2 = (unsigned)__shfl((int)h0a, sB);
        unsigned b2 = (unsigned)__shfl((int)h1a, sB);
        unsigned a3 = (unsigned)__shfl((int)h0b, sB);
        unsigned b3 = (unsigned)__shfl((int)h1b, sB);
        bool losel = (lg < 2);
        uint4 pw;
        pw.x = losel ? a0 : b0;   // j = lg*8 + {0,1}
        pw.y = losel ? a1 : b1;   // j = lg*8 + {2,3}
        pw.z = losel ? a2 : b2;   // j = lg*8 + {4,5}
        pw.w = losel ? a3 : b3;   // j = lg*8 + {6,7}
        s16x8 pf = __builtin_bit_cast(s16x8, pw);
        // ---- PV swapped: O[c][i] += V[c][j] P[j][i]; 4 batches of 4 vfr ----
        int vswz = (lg * 16) ^ (((lr >> 1) & 3) << 4);
        __builtin_amdgcn_s_setprio(1);
#pragma unroll
        for (int bt = 0; bt < 4; bt++) {
            s16x8 vfr[4];
#pragma unroll
            for (int c4 = 0; c4 < 4; c4++)
                vfr[c4] = *(const s16x8*)(Vs + ((bt * 4 + c4) * 16 + lr) * 64 + vswz);
#pragma unroll
            for (int c4 = 0; c4 < 4; c4++)
                O[bt * 4 + c4] = mfma16(vfr[c4], pf, O[bt * 4 + c4]);
        }
        __builtin_amdgcn_s_setprio(0);
        // ---- barrier1: all waves done reading Vs; then restage V ----
        __syncthreads();
        if (jt < 63) STAGEV(jt + 1);
        asm volatile("s_waitcnt vmcnt(0)" ::: "memory");
        __syncthreads();   // barrier2: K(t+1) and V(t+1) in LDS
        buf ^= 1;
    }

    // ---- l: reduce over the 4 lg lane-groups (row = i0 + lr) ----
    lsum += __shfl_xor(lsum, 16);
    lsum += __shfl_xor(lsum, 32);
    size_t sb = (size_t)(s * Bb + b);
    if (lg == 0)
        lp[sb * Nn + i0 + lr] = lsum;
    // ---- fp32 partials, [n][c] layout; lane writes 4 consecutive c ----
    float* ob = OPT + sb * Nn * Cc;
#pragma unroll
    for (int ct = 0; ct < 16; ct++)
        *(f32x4*)(ob + (size_t)(i0 + lr) * Cc + ct * 16 + lg * 4) = O[ct];
#undef STAGEK
#undef STAGEV
}

// ---------------- merge partials + transpose + epilogue ----------------
// out[b][c][n] = gamma * (OPT0+OPT1)[n][c] / (l0+l1)[n] + x[b][c][n]
__global__ void __launch_bounds__(256)
merge(const float* __restrict__ OPT, const float* __restrict__ lp,
      const float* __restrict__ x, const float* __restrict__ gamma,
      float* __restrict__ out) {
    int b = blockIdx.z, c0 = blockIdx.y * 64, n0 = blockIdx.x * 64;
    __shared__ float tile[64][65];
    __shared__ float linv[64];
    int t = threadIdx.x;
    if (t < 64) {
        float sum = lp[(size_t)b * Nn + n0 + t] + lp[(size_t)(Bb + b) * Nn + n0 + t];
        linv[t] = 1.0f / sum;
    }
    __syncthreads();
    float g = gamma[0];
    int r = t >> 2, q = t & 3;
    const float* p0 = OPT + ((size_t)b * Nn + n0 + r) * Cc + c0 + q * 16;
    const float* p1 = OPT + ((size_t)(Bb + b) * Nn + n0 + r) * Cc + c0 + q * 16;
    float sc = g * linv[r];
#pragma unroll
    for (int j = 0; j < 4; j++) {
        float4 a0 = *(const float4*)(p0 + j * 4);
        float4 a1 = *(const float4*)(p1 + j * 4);
        tile[r][q * 16 + j * 4 + 0] = sc * (a0.x + a1.x);
        tile[r][q * 16 + j * 4 + 1] = sc * (a0.y + a1.y);
        tile[r][q * 16 + j * 4 + 2] = sc * (a0.z + a1.z);
        tile[r][q * 16 + j * 4 + 3] = sc * (a0.w + a1.w);
    }
    __syncthreads();
    const float* xp = x + ((size_t)b * Cc + c0 + r) * Nn + n0 + q * 16;
    float* op = out + ((size_t)b * Cc + c0 + r) * Nn + n0 + q * 16;
#pragma unroll
    for (int j = 0; j < 4; j++) {
        float4 xv = *(const float4*)(xp + j * 4);
        float4 o4;
        o4.x = tile[q * 16 + j * 4 + 0][r] + xv.x;
        o4.y = tile[q * 16 + j * 4 + 1][r] + xv.y;
        o4.z = tile[q * 16 + j * 4 + 2][r] + xv.z;
        o4.w = tile[q * 16 + j * 4 + 3][r] + xv.w;
        *(float4*)(op + j * 4) = o4;
    }
}

extern "C" void kernel_launch(void* const* d_in, const int* in_sizes, int n_in,
                              void* d_out, int out_size, void* d_ws, size_t ws_size,
                              hipStream_t stream) {
    (void)in_sizes; (void)n_in; (void)out_size; (void)ws_size;
    const float* x     = (const float*)d_in[0];
    const float* Wq    = (const float*)d_in[1];
    const float* bq    = (const float*)d_in[2];
    const float* Wk    = (const float*)d_in[3];
    const float* bk    = (const float*)d_in[4];
    const float* Wv    = (const float*)d_in[5];
    const float* bv    = (const float*)d_in[6];
    const float* gamma = (const float*)d_in[7];
    float* out = (float*)d_out;

    const size_t XTN = (size_t)Bb * Nn * Cc;   // 4,194,304 elements
    const size_t VSZ = (size_t)Bb * Cc * NV;   // padded V
    unsigned short* xT  = (unsigned short*)d_ws;
    unsigned short* Wbf = xT + XTN;
    unsigned short* qT  = Wbf + 3 * Cc * Cc;
    unsigned short* kT  = qT + XTN;
    unsigned short* vv  = kT + XTN;
    float*          OPT = (float*)(vv + VSZ);        // 2 * XTN fp32 = 32MB
    float*          lp  = OPT + 2 * XTN;             // 2*B*N fp32

    hipLaunchKernelGGL(prep_w, dim3(96), dim3(256), 0, stream, Wq, Wk, Wv, Wbf);
    hipLaunchKernelGGL(transpose_x, dim3(Nn / 64, Cc / 64, Bb), dim3(256), 0, stream, x, xT);
    hipLaunchKernelGGL(proj, dim3(Nn / 64, 3, Bb), dim3(256), 0, stream,
                       xT, Wbf, bq, bk, bv, qT, kT, vv);
    hipLaunchKernelGGL(attn, dim3(512), dim3(256), 0, stream,
                       qT, kT, vv, OPT, lp);
    hipLaunchKernelGGL(merge, dim3(Nn / 64, Cc / 64, Bb), dim3(256), 0, stream,
                       OPT, lp, x, gamma, out);
}

// Round 18
// 188.830 us; speedup vs baseline: 4.9952x; 1.0750x over previous
//
#include <hip/hip_runtime.h>
#include <hip/hip_bf16.h>

#define Bb 4
#define Cc 256
#define Nn 4096
#define NV 4160  // V row stride (padded; addresses computed explicitly)

typedef short s16x8 __attribute__((ext_vector_type(8)));
typedef float f32x4 __attribute__((ext_vector_type(4)));

__device__ __forceinline__ unsigned short f2bf(float f) {
    unsigned u = __builtin_bit_cast(unsigned, f);
    u += 0x7FFFu + ((u >> 16) & 1u);
    return (unsigned short)(u >> 16);
}

__device__ __forceinline__ unsigned pk2bf(float a, float b) {
    return (unsigned)f2bf(a) | ((unsigned)f2bf(b) << 16);
}

__device__ __forceinline__ f32x4 mfma16(s16x8 a, s16x8 b, f32x4 c) {
    return __builtin_amdgcn_mfma_f32_16x16x32_bf16(a, b, c, 0, 0, 0);
}

#if __has_builtin(__builtin_amdgcn_global_load_lds)
#define GL16(g, sdst)                                                              \
    __builtin_amdgcn_global_load_lds(                                              \
        (const __attribute__((address_space(1))) unsigned int*)(g),                \
        (__attribute__((address_space(3))) unsigned int*)(sdst), 16, 0, 0)
#else
#define GL16(g, sdst)                                                              \
    do {                                                                           \
        *(s16x8*)((char*)(sdst) + (threadIdx.x & 63) * 16) = *(const s16x8*)(g);   \
    } while (0)
#endif

// ---------------- prep: W fp32 -> bf16 ----------------
__global__ void prep_w(const float* __restrict__ Wq, const float* __restrict__ Wk,
                       const float* __restrict__ Wv, unsigned short* __restrict__ Wbf) {
    int idx = (blockIdx.x * 256 + threadIdx.x) * 8;  // < 3*65536
    int mat = idx >> 16;
    int off = idx & 65535;
    const float* src = (mat == 0) ? Wq : ((mat == 1) ? Wk : Wv);
    float4 a = *(const float4*)(src + off);
    float4 b = *(const float4*)(src + off + 4);
    s16x8 o;
    o[0] = (short)f2bf(a.x); o[1] = (short)f2bf(a.y);
    o[2] = (short)f2bf(a.z); o[3] = (short)f2bf(a.w);
    o[4] = (short)f2bf(b.x); o[5] = (short)f2bf(b.y);
    o[6] = (short)f2bf(b.z); o[7] = (short)f2bf(b.w);
    *(s16x8*)(Wbf + idx) = o;
}

// ---------------- transpose: x[b][c][n] fp32 -> xT[b][n][c] bf16 ----------------
__global__ void transpose_x(const float* __restrict__ x, unsigned short* __restrict__ xT) {
    int b = blockIdx.z, c0 = blockIdx.y * 64, n0 = blockIdx.x * 64;
    __shared__ float tile[64][65];
    int t = threadIdx.x;
    int r = t >> 2, q = t & 3;
    const float* src = x + ((size_t)(b * Cc + c0 + r)) * Nn + n0 + q * 16;
#pragma unroll
    for (int j = 0; j < 4; j++) {
        float4 v4 = *(const float4*)(src + j * 4);
        tile[r][q * 16 + j * 4 + 0] = v4.x;
        tile[r][q * 16 + j * 4 + 1] = v4.y;
        tile[r][q * 16 + j * 4 + 2] = v4.z;
        tile[r][q * 16 + j * 4 + 3] = v4.w;
    }
    __syncthreads();
    unsigned short* dst = xT + ((size_t)b * Nn + n0 + r) * Cc + c0 + q * 16;
    s16x8 o0, o1;
#pragma unroll
    for (int j = 0; j < 8; j++) o0[j] = (short)f2bf(tile[q * 16 + j][r]);
#pragma unroll
    for (int j = 0; j < 8; j++) o1[j] = (short)f2bf(tile[q * 16 + 8 + j][r]);
    *(s16x8*)dst = o0;
    *(s16x8*)(dst + 8) = o1;
}

// ---------------- projections ----------------
__global__ void proj(const unsigned short* __restrict__ xT, const unsigned short* __restrict__ Wbf,
                     const float* __restrict__ bq, const float* __restrict__ bk,
                     const float* __restrict__ bv,
                     unsigned short* __restrict__ qT, unsigned short* __restrict__ kT,
                     unsigned short* __restrict__ vO) {
    int nt0 = blockIdx.x * 64;
    int mat = blockIdx.y;
    int b   = blockIdx.z;
    int t = threadIdx.x, w = t >> 6, l = t & 63;
    int lr = l & 15, lg = l >> 4;
    const unsigned short* Wm  = Wbf + mat * (Cc * Cc);
    const float* bias = (mat == 0) ? bq : ((mat == 1) ? bk : bv);
    const unsigned short* xTb = xT + (size_t)b * Nn * Cc;

    if (mat < 2) {
        unsigned short* out = ((mat == 0) ? qT : kT) + (size_t)b * Nn * Cc;
        int nrow = nt0 + w * 16;
        s16x8 af[8];
#pragma unroll
        for (int kk = 0; kk < 8; kk++)
            af[kk] = *(const s16x8*)(xTb + (nrow + lr) * Cc + kk * 32 + lg * 8);
        for (int ct = 0; ct < 16; ct++) {
            f32x4 acca = {0, 0, 0, 0}, accb = {0, 0, 0, 0};
#pragma unroll
            for (int kk = 0; kk < 8; kk += 2) {
                s16x8 bfa = *(const s16x8*)(Wm + (ct * 16 + lr) * Cc + kk * 32 + lg * 8);
                s16x8 bfb = *(const s16x8*)(Wm + (ct * 16 + lr) * Cc + (kk + 1) * 32 + lg * 8);
                acca = mfma16(af[kk], bfa, acca);
                accb = mfma16(af[kk + 1], bfb, accb);
            }
            f32x4 acc = acca + accb;
            float bb = bias[ct * 16 + lr];
#pragma unroll
            for (int r = 0; r < 4; r++)
                out[(nrow + lg * 4 + r) * Cc + ct * 16 + lr] = f2bf(acc[r] + bb);
        }
    } else {
        unsigned short* out = vO + (size_t)b * Cc * NV;
        for (int mt = 0; mt < 4; mt++) {
            int crow = (w * 4 + mt) * 16;
            s16x8 af[8];
#pragma unroll
            for (int kk = 0; kk < 8; kk++)
                af[kk] = *(const s16x8*)(Wm + (crow + lr) * Cc + kk * 32 + lg * 8);
#pragma unroll
            for (int nt = 0; nt < 4; nt++) {
                f32x4 acca = {0, 0, 0, 0}, accb = {0, 0, 0, 0};
#pragma unroll
                for (int kk = 0; kk < 8; kk += 2) {
                    s16x8 bfa = *(const s16x8*)(xTb + (nt0 + nt * 16 + lr) * Cc + kk * 32 + lg * 8);
                    s16x8 bfb = *(const s16x8*)(xTb + (nt0 + nt * 16 + lr) * Cc + (kk + 1) * 32 + lg * 8);
                    acca = mfma16(af[kk], bfa, acca);
                    accb = mfma16(af[kk + 1], bfb, accb);
                }
                f32x4 acc = acca + accb;
#pragma unroll
                for (int r = 0; r < 4; r++) {
                    float bb = bias[crow + lg * 4 + r];
                    out[(size_t)(crow + lg * 4 + r) * NV + nt0 + nt * 16 + lr] = f2bf(acc[r] + bb);
                }
            }
        }
    }
}

// ---------------- fused flash attention: cross-tile pipelined ----------
// R14 base (in-reg P via swapped MFMA, K+V LDS dbuf, S=2 combo/XCD,
// 2 independent blocks/CU) restructured for T15-style cross-tile ILP:
//   iter t: issue STAGE K(t+2)->Kbuf[t%2], V(t+1)->Vbuf[(t+1)%2]  (early);
//           QK(t+1)   [independent of tile t's softmax/PV -> interleaves];
//           softmax(t) + remap + PV(t);
//           one __syncthreads (implicit full drain; loads had ~1 tile in flight)
// E double-state (named En0/En1 -> E0/E1; rule #20). One barrier/tile (was 2).
__global__ void __launch_bounds__(256, 2)
attn(const unsigned short* __restrict__ qT, const unsigned short* __restrict__ kT,
     const unsigned short* __restrict__ vv,
     float* __restrict__ OPT, float* __restrict__ lp) {
    int id = blockIdx.x;
    int bs = id & 7, b = bs >> 1, s = bs & 1, iblk = id >> 3;  // iblk 0..63
    int t = threadIdx.x, w = t >> 6, l = t & 63;
    int lr = l & 15, lg = l >> 4;
    int i0 = iblk * 64 + w * 16;

    __shared__ char Ks[2][16384];   // K tile dbuf: 32 rows x 512B (swz (row&7)<<4)
    __shared__ char Vs[2][16384];   // V tile dbuf: 256 rows x 64B (swz ((row>>1)&3)<<4)

    const unsigned short* qb = qT + ((size_t)b * Nn + i0) * Cc;
    const char* kbase = (const char*)(kT + ((size_t)b * Nn + s * 2048) * Cc);
    const char* vbase = (const char*)(vv + (size_t)b * Cc * NV + s * 2048);

    s16x8 qf[8];
#pragma unroll
    for (int kk = 0; kk < 8; kk++)
        qf[kk] = *(const s16x8*)(qb + lr * Cc + kk * 32 + lg * 8);

    f32x4 O[16];  // O[ct][r] = O[c = ct*16 + lg*4 + r][i = i0 + lr]
#pragma unroll
    for (int ct = 0; ct < 16; ct++) O[ct] = {0, 0, 0, 0};
    float lsum = 0.f;
    const float L2E = 1.44269504088896340736f;

#define STAGEK(bufi, jt)                                                        \
    {                                                                           \
        const char* ksl_ = kbase + (size_t)(jt) * 16384;                        \
        _Pragma("unroll") for (int i_ = 0; i_ < 4; i_++) {                      \
            int chunk_ = w * 4 + i_;                                            \
            int L_ = chunk_ * 1024 + l * 16;                                    \
            int row_ = L_ >> 9;                                                 \
            GL16(ksl_ + (L_ ^ ((row_ & 7) << 4)), &Ks[bufi][chunk_ * 1024]);    \
        }                                                                       \
    }

#define STAGEV(bufi, jt)                                                        \
    {                                                                           \
        _Pragma("unroll") for (int i_ = 0; i_ < 4; i_++) {                      \
            int chunk_ = w * 4 + i_;                                            \
            int row_ = chunk_ * 16 + (l >> 2);                                  \
            int colb_ = ((l & 3) * 16) ^ (((l >> 3) & 3) << 4);                 \
            GL16(vbase + (size_t)row_ * (NV * 2) + (size_t)(jt) * 64 + colb_,   \
                 &Vs[bufi][chunk_ * 1024]);                                     \
        }                                                                       \
    }

// QK^T swapped into (e0,e1): E^T[j][i]; lane (lr,lg) reg r: j=lg*4+r, i=lr
#define QKT(e0, e1, bufi)                                                       \
    {                                                                           \
        const char* ksb_ = Ks[bufi];                                            \
        __builtin_amdgcn_s_setprio(1);                                          \
        _Pragma("unroll") for (int kk = 0; kk < 8; kk++) {                      \
            int cb_ = (kk * 64 + lg * 16) ^ ((lr & 7) << 4);                    \
            s16x8 k0_ = *(const s16x8*)(ksb_ + lr * 512 + cb_);                 \
            s16x8 k1_ = *(const s16x8*)(ksb_ + (16 + lr) * 512 + cb_);          \
            e0 = mfma16(k0_, qf[kk], e0);                                       \
            e1 = mfma16(k1_, qf[kk], e1);                                       \
        }                                                                       \
        __builtin_amdgcn_s_setprio(0);                                          \
    }

    // ---- prologue: K(0),V(0),K(1) staged; drain; E = QK(0) ----
    STAGEK(0, 0);
    STAGEV(0, 0);
    STAGEK(1, 1);
    asm volatile("s_waitcnt vmcnt(0)" ::: "memory");
    __syncthreads();
    f32x4 E0 = {0, 0, 0, 0}, E1 = {0, 0, 0, 0};
    QKT(E0, E1, 0);

    for (int jt = 0; jt < 64; jt++) {
        // ---- early stage: K(t+2) -> Kbuf[t%2], V(t+1) -> Vbuf[(t+1)%2] ----
        if (jt <= 61) STAGEK(jt & 1, jt + 2);
        if (jt <= 62) STAGEV((jt + 1) & 1, jt + 1);
        // ---- QK(t+1): independent of softmax(t)/PV(t) -> interleaves ----
        f32x4 En0 = {0, 0, 0, 0}, En1 = {0, 0, 0, 0};
        QKT(En0, En1, (jt + 1) & 1);
        // ---- V fragments for tile t ----
        const char* vsb = Vs[jt & 1];
        int vswz = (lg * 16) ^ (((lr >> 1) & 3) << 4);
        s16x8 vfr[16];
#pragma unroll
        for (int ct = 0; ct < 16; ct++)
            vfr[ct] = *(const s16x8*)(vsb + (ct * 16 + lr) * 64 + vswz);
        // ---- shift-free softmax on tile t ----
        float p0[4], p1[4];
#pragma unroll
        for (int r = 0; r < 4; r++) {
            p0[r] = exp2f(E0[r] * L2E);
            p1[r] = exp2f(E1[r] * L2E);
            lsum += p0[r] + p1[r];
        }
        // ---- register remap to B-frag[k=j][col=i] ----
        unsigned h0a = pk2bf(p0[0], p0[1]), h0b = pk2bf(p0[2], p0[3]);
        unsigned h1a = pk2bf(p1[0], p1[1]), h1b = pk2bf(p1[2], p1[3]);
        int sA = lr + ((lg & 1) << 5);
        int sB = sA + 16;
        unsigned a0 = (unsigned)__shfl((int)h0a, sA);
        unsigned b0 = (unsigned)__shfl((int)h1a, sA);
        unsigned a1 = (unsigned)__shfl((int)h0b, sA);
        unsigned b1 = (unsigned)__shfl((int)h1b, sA);
        unsigned a2 = (unsigned)__shfl((int)h0a, sB);
        unsigned b2 = (unsigned)__shfl((int)h1a, sB);
        unsigned a3 = (unsigned)__shfl((int)h0b, sB);
        unsigned b3 = (unsigned)__shfl((int)h1b, sB);
        bool losel = (lg < 2);
        uint4 pw;
        pw.x = losel ? a0 : b0;
        pw.y = losel ? a1 : b1;
        pw.z = losel ? a2 : b2;
        pw.w = losel ? a3 : b3;
        s16x8 pf = __builtin_bit_cast(s16x8, pw);
        // ---- PV: O[c][i] += V[c][j] P[j][i] ----
        __builtin_amdgcn_s_setprio(1);
#pragma unroll
        for (int ct = 0; ct < 16; ct++)
            O[ct] = mfma16(vfr[ct], pf, O[ct]);
        __builtin_amdgcn_s_setprio(0);
        // ---- single barrier (implicit full drain covers the early stages) ----
        if (jt < 63) __syncthreads();
        E0 = En0;
        E1 = En1;
    }

    // ---- l: reduce over the 4 lg lane-groups (row = i0 + lr) ----
    lsum += __shfl_xor(lsum, 16);
    lsum += __shfl_xor(lsum, 32);
    size_t sb = (size_t)(s * Bb + b);
    if (lg == 0)
        lp[sb * Nn + i0 + lr] = lsum;
    // ---- fp32 partials, [n][c] layout; lane writes 4 consecutive c ----
    float* ob = OPT + sb * Nn * Cc;
#pragma unroll
    for (int ct = 0; ct < 16; ct++)
        *(f32x4*)(ob + (size_t)(i0 + lr) * Cc + ct * 16 + lg * 4) = O[ct];
#undef STAGEK
#undef STAGEV
#undef QKT
}

// ---------------- merge partials + transpose + epilogue ----------------
// out[b][c][n] = gamma * (OPT0+OPT1)[n][c] / (l0+l1)[n] + x[b][c][n]
__global__ void __launch_bounds__(256)
merge(const float* __restrict__ OPT, const float* __restrict__ lp,
      const float* __restrict__ x, const float* __restrict__ gamma,
      float* __restrict__ out) {
    int b = blockIdx.z, c0 = blockIdx.y * 64, n0 = blockIdx.x * 64;
    __shared__ float tile[64][65];
    __shared__ float linv[64];
    int t = threadIdx.x;
    if (t < 64) {
        float sum = lp[(size_t)b * Nn + n0 + t] + lp[(size_t)(Bb + b) * Nn + n0 + t];
        linv[t] = 1.0f / sum;
    }
    __syncthreads();
    float g = gamma[0];
    int r = t >> 2, q = t & 3;
    const float* p0 = OPT + ((size_t)b * Nn + n0 + r) * Cc + c0 + q * 16;
    const float* p1 = OPT + ((size_t)(Bb + b) * Nn + n0 + r) * Cc + c0 + q * 16;
    float sc = g * linv[r];
#pragma unroll
    for (int j = 0; j < 4; j++) {
        float4 a0 = *(const float4*)(p0 + j * 4);
        float4 a1 = *(const float4*)(p1 + j * 4);
        tile[r][q * 16 + j * 4 + 0] = sc * (a0.x + a1.x);
        tile[r][q * 16 + j * 4 + 1] = sc * (a0.y + a1.y);
        tile[r][q * 16 + j * 4 + 2] = sc * (a0.z + a1.z);
        tile[r][q * 16 + j * 4 + 3] = sc * (a0.w + a1.w);
    }
    __syncthreads();
    const float* xp = x + ((size_t)b * Cc + c0 + r) * Nn + n0 + q * 16;
    float* op = out + ((size_t)b * Cc + c0 + r) * Nn + n0 + q * 16;
#pragma unroll
    for (int j = 0; j < 4; j++) {
        float4 xv = *(const float4*)(xp + j * 4);
        float4 o4;
        o4.x = tile[q * 16 + j * 4 + 0][r] + xv.x;
        o4.y = tile[q * 16 + j * 4 + 1][r] + xv.y;
        o4.z = tile[q * 16 + j * 4 + 2][r] + xv.z;
        o4.w = tile[q * 16 + j * 4 + 3][r] + xv.w;
        *(float4*)(op + j * 4) = o4;
    }
}

extern "C" void kernel_launch(void* const* d_in, const int* in_sizes, int n_in,
                              void* d_out, int out_size, void* d_ws, size_t ws_size,
                              hipStream_t stream) {
    (void)in_sizes; (void)n_in; (void)out_size; (void)ws_size;
    const float* x     = (const float*)d_in[0];
    const float* Wq    = (const float*)d_in[1];
    const float* bq    = (const float*)d_in[2];
    const float* Wk    = (const float*)d_in[3];
    const float* bk    = (const float*)d_in[4];
    const float* Wv    = (const float*)d_in[5];
    const float* bv    = (const float*)d_in[6];
    const float* gamma = (const float*)d_in[7];
    float* out = (float*)d_out;

    const size_t XTN = (size_t)Bb * Nn * Cc;   // 4,194,304 elements
    const size_t VSZ = (size_t)Bb * Cc * NV;   // padded V
    unsigned short* xT  = (unsigned short*)d_ws;
    unsigned short* Wbf = xT + XTN;
    unsigned short* qT  = Wbf + 3 * Cc * Cc;
    unsigned short* kT  = qT + XTN;
    unsigned short* vv  = kT + XTN;
    float*          OPT = (float*)(vv + VSZ);        // 2 * XTN fp32 = 32MB
    float*          lp  = OPT + 2 * XTN;             // 2*B*N fp32

    hipLaunchKernelGGL(prep_w, dim3(96), dim3(256), 0, stream, Wq, Wk, Wv, Wbf);
    hipLaunchKernelGGL(transpose_x, dim3(Nn / 64, Cc / 64, Bb), dim3(256), 0, stream, x, xT);
    hipLaunchKernelGGL(proj, dim3(Nn / 64, 3, Bb), dim3(256), 0, stream,
                       xT, Wbf, bq, bk, bv, qT, kT, vv);
    hipLaunchKernelGGL(attn, dim3(512), dim3(256), 0, stream,
                       qT, kT, vv, OPT, lp);
    hipLaunchKernelGGL(merge, dim3(Nn / 64, Cc / 64, Bb), dim3(256), 0, stream,
                       OPT, lp, x, gamma, out);
}

// Round 19
// 180.205 us; speedup vs baseline: 5.2343x; 1.0479x over previous
//
#include <hip/hip_runtime.h>
#include <hip/hip_bf16.h>

#define Bb 4
#define Cc 256
#define Nn 4096
#define NV 4160  // V row stride (padded; addresses computed explicitly)

typedef short s16x8 __attribute__((ext_vector_type(8)));
typedef short s16x4 __attribute__((ext_vector_type(4)));
typedef float f32x4 __attribute__((ext_vector_type(4)));

__device__ __forceinline__ unsigned short f2bf(float f) {
    unsigned u = __builtin_bit_cast(unsigned, f);
    u += 0x7FFFu + ((u >> 16) & 1u);
    return (unsigned short)(u >> 16);
}
__device__ __forceinline__ float bf2f(unsigned short u) {
    unsigned v = ((unsigned)u) << 16;
    return __builtin_bit_cast(float, v);
}

__device__ __forceinline__ f32x4 mfma16(s16x8 a, s16x8 b, f32x4 c) {
    return __builtin_amdgcn_mfma_f32_16x16x32_bf16(a, b, c, 0, 0, 0);
}

#if __has_builtin(__builtin_amdgcn_global_load_lds)
#define GL16(g, sdst)                                                              \
    __builtin_amdgcn_global_load_lds(                                              \
        (const __attribute__((address_space(1))) unsigned int*)(g),                \
        (__attribute__((address_space(3))) unsigned int*)(sdst), 16, 0, 0)
#else
#define GL16(g, sdst)                                                              \
    do {                                                                           \
        *(s16x8*)((char*)(sdst) + (threadIdx.x & 63) * 16) = *(const s16x8*)(g);   \
    } while (0)
#endif

// ---------------- prep: W fp32 -> bf16 ----------------
__global__ void prep_w(const float* __restrict__ Wq, const float* __restrict__ Wk,
                       const float* __restrict__ Wv, unsigned short* __restrict__ Wbf) {
    int idx = (blockIdx.x * 256 + threadIdx.x) * 8;  // < 3*65536
    int mat = idx >> 16;
    int off = idx & 65535;
    const float* src = (mat == 0) ? Wq : ((mat == 1) ? Wk : Wv);
    float4 a = *(const float4*)(src + off);
    float4 b = *(const float4*)(src + off + 4);
    s16x8 o;
    o[0] = (short)f2bf(a.x); o[1] = (short)f2bf(a.y);
    o[2] = (short)f2bf(a.z); o[3] = (short)f2bf(a.w);
    o[4] = (short)f2bf(b.x); o[5] = (short)f2bf(b.y);
    o[6] = (short)f2bf(b.z); o[7] = (short)f2bf(b.w);
    *(s16x8*)(Wbf + idx) = o;
}

// ---------------- transpose: x[b][c][n] fp32 -> xT[b][n][c] bf16 ----------------
__global__ void transpose_x(const float* __restrict__ x, unsigned short* __restrict__ xT) {
    int b = blockIdx.z, c0 = blockIdx.y * 64, n0 = blockIdx.x * 64;
    __shared__ float tile[64][65];
    int t = threadIdx.x;
    int r = t >> 2, q = t & 3;
    const float* src = x + ((size_t)(b * Cc + c0 + r)) * Nn + n0 + q * 16;
#pragma unroll
    for (int j = 0; j < 4; j++) {
        float4 v4 = *(const float4*)(src + j * 4);
        tile[r][q * 16 + j * 4 + 0] = v4.x;
        tile[r][q * 16 + j * 4 + 1] = v4.y;
        tile[r][q * 16 + j * 4 + 2] = v4.z;
        tile[r][q * 16 + j * 4 + 3] = v4.w;
    }
    __syncthreads();
    unsigned short* dst = xT + ((size_t)b * Nn + n0 + r) * Cc + c0 + q * 16;
    s16x8 o0, o1;
#pragma unroll
    for (int j = 0; j < 8; j++) o0[j] = (short)f2bf(tile[q * 16 + j][r]);
#pragma unroll
    for (int j = 0; j < 8; j++) o1[j] = (short)f2bf(tile[q * 16 + 8 + j][r]);
    *(s16x8*)dst = o0;
    *(s16x8*)(dst + 8) = o1;
}

// ---------------- projections ----------------
__global__ void proj(const unsigned short* __restrict__ xT, const unsigned short* __restrict__ Wbf,
                     const float* __restrict__ bq, const float* __restrict__ bk,
                     const float* __restrict__ bv,
                     unsigned short* __restrict__ qT, unsigned short* __restrict__ kT,
                     unsigned short* __restrict__ vO) {
    int nt0 = blockIdx.x * 64;
    int mat = blockIdx.y;
    int b   = blockIdx.z;
    int t = threadIdx.x, w = t >> 6, l = t & 63;
    int lr = l & 15, lg = l >> 4;
    const unsigned short* Wm  = Wbf + mat * (Cc * Cc);
    const float* bias = (mat == 0) ? bq : ((mat == 1) ? bk : bv);
    const unsigned short* xTb = xT + (size_t)b * Nn * Cc;

    if (mat < 2) {
        unsigned short* out = ((mat == 0) ? qT : kT) + (size_t)b * Nn * Cc;
        int nrow = nt0 + w * 16;
        s16x8 af[8];
#pragma unroll
        for (int kk = 0; kk < 8; kk++)
            af[kk] = *(const s16x8*)(xTb + (nrow + lr) * Cc + kk * 32 + lg * 8);
        for (int ct = 0; ct < 16; ct++) {
            f32x4 acca = {0, 0, 0, 0}, accb = {0, 0, 0, 0};
#pragma unroll
            for (int kk = 0; kk < 8; kk += 2) {
                s16x8 bfa = *(const s16x8*)(Wm + (ct * 16 + lr) * Cc + kk * 32 + lg * 8);
                s16x8 bfb = *(const s16x8*)(Wm + (ct * 16 + lr) * Cc + (kk + 1) * 32 + lg * 8);
                acca = mfma16(af[kk], bfa, acca);
                accb = mfma16(af[kk + 1], bfb, accb);
            }
            f32x4 acc = acca + accb;
            float bb = bias[ct * 16 + lr];
#pragma unroll
            for (int r = 0; r < 4; r++)
                out[(nrow + lg * 4 + r) * Cc + ct * 16 + lr] = f2bf(acc[r] + bb);
        }
    } else {
        unsigned short* out = vO + (size_t)b * Cc * NV;
        for (int mt = 0; mt < 4; mt++) {
            int crow = (w * 4 + mt) * 16;
            s16x8 af[8];
#pragma unroll
            for (int kk = 0; kk < 8; kk++)
                af[kk] = *(const s16x8*)(Wm + (crow + lr) * Cc + kk * 32 + lg * 8);
#pragma unroll
            for (int nt = 0; nt < 4; nt++) {
                f32x4 acca = {0, 0, 0, 0}, accb = {0, 0, 0, 0};
#pragma unroll
                for (int kk = 0; kk < 8; kk += 2) {
                    s16x8 bfa = *(const s16x8*)(xTb + (nt0 + nt * 16 + lr) * Cc + kk * 32 + lg * 8);
                    s16x8 bfb = *(const s16x8*)(xTb + (nt0 + nt * 16 + lr) * Cc + (kk + 1) * 32 + lg * 8);
                    acca = mfma16(af[kk], bfa, acca);
                    accb = mfma16(af[kk + 1], bfb, accb);
                }
                f32x4 acc = acca + accb;
#pragma unroll
                for (int r = 0; r < 4; r++) {
                    float bb = bias[crow + lg * 4 + r];
                    out[(size_t)(crow + lg * 4 + r) * NV + nt0 + nt * 16 + lr] = f2bf(acc[r] + bb);
                }
            }
        }
    }
}

// ---------------- fused flash attention (R11 structure, best measured) -------
// 512 blocks x 256 thr (4 waves x 16 i-rows), S=2, id&7=(b,s) combo -> one
// combo per XCD (1MB K + 1MB V slice L2-resident, 64 lockstep blocks),
// 2 independent blocks/CU (LDS 68KB). K+V LDS-staged dbuf via global_load_lds
// with both-sides XOR swizzles. Shift-free softmax, wave-synchronous P
// roundtrip. ONLY change vs R11: partials stored as bf16 (R15-validated
// precision; halves OPT traffic in attn-write and merge-read).
__global__ void __launch_bounds__(256, 2)
attn(const unsigned short* __restrict__ qT, const unsigned short* __restrict__ kT,
     const unsigned short* __restrict__ vv,
     unsigned short* __restrict__ OPT, float* __restrict__ lp) {
    int id = blockIdx.x;
    int bs = id & 7, b = bs >> 1, s = bs & 1, iblk = id >> 3;  // iblk 0..63
    int t = threadIdx.x, w = t >> 6, l = t & 63;
    int lr = l & 15, lg = l >> 4;
    int i0 = iblk * 64 + w * 16;

    __shared__ char Ks[2][16384];              // K tile dbuf: 32 rows x 512B
    __shared__ char Vs[2][16384];              // V tile dbuf: 256 rows x 64B
    __shared__ unsigned short P_lds[4][512];   // per-wave [16][32] bf16
    unsigned short* pl = P_lds[w];

    const unsigned short* qb = qT + ((size_t)b * Nn + i0) * Cc;
    const char* kbase = (const char*)(kT + ((size_t)b * Nn + s * 2048) * Cc);
    const char* vbase = (const char*)(vv + (size_t)b * Cc * NV + s * 2048);

    s16x8 qf[8];
#pragma unroll
    for (int kk = 0; kk < 8; kk++)
        qf[kk] = *(const s16x8*)(qb + lr * Cc + kk * 32 + lg * 8);

    f32x4 O[16];
#pragma unroll
    for (int ct = 0; ct < 16; ct++) O[ct] = {0, 0, 0, 0};
    float lsum[4] = {0, 0, 0, 0};
    const float L2E = 1.44269504088896340736f;

#define STAGEK(bufi, jt)                                                        \
    {                                                                           \
        const char* ksl_ = kbase + (size_t)(jt) * 16384;                        \
        _Pragma("unroll") for (int i_ = 0; i_ < 4; i_++) {                      \
            int chunk_ = w * 4 + i_;                                            \
            int L_ = chunk_ * 1024 + l * 16;                                    \
            int row_ = L_ >> 9;                                                 \
            GL16(ksl_ + (L_ ^ ((row_ & 7) << 4)), &Ks[bufi][chunk_ * 1024]);    \
        }                                                                       \
    }

#define STAGEV(bufi, jt)                                                        \
    {                                                                           \
        _Pragma("unroll") for (int i_ = 0; i_ < 4; i_++) {                      \
            int chunk_ = w * 4 + i_;                                            \
            int row_ = chunk_ * 16 + (l >> 2);                                  \
            int colb_ = ((l & 3) * 16) ^ (((l >> 3) & 3) << 4);                 \
            GL16(vbase + (size_t)row_ * (NV * 2) + (size_t)(jt) * 64 + colb_,   \
                 &Vs[bufi][chunk_ * 1024]);                                     \
        }                                                                       \
    }

    STAGEK(0, 0);
    STAGEV(0, 0);
    asm volatile("s_waitcnt vmcnt(0)" ::: "memory");
    __syncthreads();
    int buf = 0;

    for (int jt = 0; jt < 64; jt++) {
        // ---- prefetch next K+V tiles into other buffer ----
        if (jt < 63) {
            STAGEK(buf ^ 1, jt + 1);
            STAGEV(buf ^ 1, jt + 1);
        }
        // ---- QK^T from K-LDS ----
        const char* ksb = Ks[buf];
        f32x4 E0 = {0, 0, 0, 0}, E1 = {0, 0, 0, 0};
#pragma unroll
        for (int kk = 0; kk < 8; kk++) {
            int cb = (kk * 64 + lg * 16) ^ ((lr & 7) << 4);
            s16x8 k0 = *(const s16x8*)(ksb + lr * 512 + cb);
            s16x8 k1 = *(const s16x8*)(ksb + (16 + lr) * 512 + cb);
            E0 = mfma16(qf[kk], k0, E0);
            E1 = mfma16(qf[kk], k1, E1);
        }
        // ---- shift-free softmax ----
        float p0[4], p1[4];
#pragma unroll
        for (int r = 0; r < 4; r++) {
            p0[r] = exp2f(E0[r] * L2E);
            p1[r] = exp2f(E1[r] * L2E);
            lsum[r] += p0[r] + p1[r];
        }
        // ---- P -> bf16 -> LDS (wave-synchronous roundtrip) ----
#pragma unroll
        for (int r = 0; r < 4; r++) {
            pl[(lg * 4 + r) * 32 + lr] = f2bf(p0[r]);
            pl[(lg * 4 + r) * 32 + 16 + lr] = f2bf(p1[r]);
        }
        // ---- V reads issued before the drain (latency absorbed together) ----
        const char* vsb = Vs[buf];
        int vswz = (lg * 16) ^ (((lr >> 1) & 3) << 4);
        s16x8 vfr[16];
#pragma unroll
        for (int ct = 0; ct < 16; ct++)
            vfr[ct] = *(const s16x8*)(vsb + (ct * 16 + lr) * 64 + vswz);
        asm volatile("s_waitcnt lgkmcnt(0)" ::: "memory");
        __builtin_amdgcn_sched_barrier(0);
        s16x8 pf = *(const s16x8*)(pl + lr * 32 + lg * 8);
        // ---- PV ----
#pragma unroll
        for (int ct = 0; ct < 16; ct++)
            O[ct] = mfma16(pf, vfr[ct], O[ct]);
        asm volatile("s_waitcnt vmcnt(0)" ::: "memory");
        __syncthreads();
        buf ^= 1;
    }

    // ---- l reduction across 16 lanes of each row group ----
#pragma unroll
    for (int r = 0; r < 4; r++) {
#pragma unroll
        for (int msk = 1; msk <= 8; msk <<= 1)
            lsum[r] += __shfl_xor(lsum[r], msk);
    }
    size_t sb = (size_t)(s * Bb + b);
    if (lr == 0) {
#pragma unroll
        for (int r = 0; r < 4; r++)
            lp[sb * Nn + i0 + lg * 4 + r] = lsum[r];
    }
    // ---- bf16 partials, [n][c] layout: 16 lr lanes contiguous in c ----
    unsigned short* ob = OPT + sb * Nn * Cc;
#pragma unroll
    for (int ct = 0; ct < 16; ct++) {
#pragma unroll
        for (int r = 0; r < 4; r++)
            ob[(size_t)(i0 + lg * 4 + r) * Cc + ct * 16 + lr] = f2bf(O[ct][r]);
    }
#undef STAGEK
#undef STAGEV
}

// ---------------- merge bf16 partials + transpose + epilogue ----------------
// out[b][c][n] = gamma * (OPT0+OPT1)[n][c] / (l0+l1)[n] + x[b][c][n]
__global__ void __launch_bounds__(256)
merge(const unsigned short* __restrict__ OPT, const float* __restrict__ lp,
      const float* __restrict__ x, const float* __restrict__ gamma,
      float* __restrict__ out) {
    int b = blockIdx.z, c0 = blockIdx.y * 64, n0 = blockIdx.x * 64;
    __shared__ float tile[64][65];
    __shared__ float linv[64];
    int t = threadIdx.x;
    if (t < 64) {
        float sum = lp[(size_t)b * Nn + n0 + t] + lp[(size_t)(Bb + b) * Nn + n0 + t];
        linv[t] = 1.0f / sum;
    }
    __syncthreads();
    float g = gamma[0];
    int r = t >> 2, q = t & 3;
    const unsigned short* p0 = OPT + ((size_t)b * Nn + n0 + r) * Cc + c0 + q * 16;
    const unsigned short* p1 = OPT + ((size_t)(Bb + b) * Nn + n0 + r) * Cc + c0 + q * 16;
    float sc = g * linv[r];
#pragma unroll
    for (int j = 0; j < 2; j++) {
        s16x8 a0 = *(const s16x8*)(p0 + j * 8);
        s16x8 a1 = *(const s16x8*)(p1 + j * 8);
#pragma unroll
        for (int e = 0; e < 8; e++)
            tile[r][q * 16 + j * 8 + e] =
                sc * (bf2f((unsigned short)a0[e]) + bf2f((unsigned short)a1[e]));
    }
    __syncthreads();
    // write rows of out: row c = c0 + r, cols n0 + q*16 .. +15
    const float* xp = x + ((size_t)b * Cc + c0 + r) * Nn + n0 + q * 16;
    float* op = out + ((size_t)b * Cc + c0 + r) * Nn + n0 + q * 16;
#pragma unroll
    for (int j = 0; j < 4; j++) {
        float4 xv = *(const float4*)(xp + j * 4);
        float4 o4;
        o4.x = tile[q * 16 + j * 4 + 0][r] + xv.x;
        o4.y = tile[q * 16 + j * 4 + 1][r] + xv.y;
        o4.z = tile[q * 16 + j * 4 + 2][r] + xv.z;
        o4.w = tile[q * 16 + j * 4 + 3][r] + xv.w;
        *(float4*)(op + j * 4) = o4;
    }
}

extern "C" void kernel_launch(void* const* d_in, const int* in_sizes, int n_in,
                              void* d_out, int out_size, void* d_ws, size_t ws_size,
                              hipStream_t stream) {
    (void)in_sizes; (void)n_in; (void)out_size; (void)ws_size;
    const float* x     = (const float*)d_in[0];
    const float* Wq    = (const float*)d_in[1];
    const float* bq    = (const float*)d_in[2];
    const float* Wk    = (const float*)d_in[3];
    const float* bk    = (const float*)d_in[4];
    const float* Wv    = (const float*)d_in[5];
    const float* bv    = (const float*)d_in[6];
    const float* gamma = (const float*)d_in[7];
    float* out = (float*)d_out;

    const size_t XTN = (size_t)Bb * Nn * Cc;   // 4,194,304 elements
    const size_t VSZ = (size_t)Bb * Cc * NV;   // padded V
    unsigned short* xT  = (unsigned short*)d_ws;
    unsigned short* Wbf = xT + XTN;
    unsigned short* qT  = Wbf + 3 * Cc * Cc;
    unsigned short* kT  = qT + XTN;
    unsigned short* vv  = kT + XTN;
    unsigned short* OPT = vv + VSZ;                  // 2 * XTN bf16 = 16MB
    float*          lp  = (float*)(OPT + 2 * XTN);   // 2*B*N fp32

    hipLaunchKernelGGL(prep_w, dim3(96), dim3(256), 0, stream, Wq, Wk, Wv, Wbf);
    hipLaunchKernelGGL(transpose_x, dim3(Nn / 64, Cc / 64, Bb), dim3(256), 0, stream, x, xT);
    hipLaunchKernelGGL(proj, dim3(Nn / 64, 3, Bb), dim3(256), 0, stream,
                       xT, Wbf, bq, bk, bv, qT, kT, vv);
    hipLaunchKernelGGL(attn, dim3(512), dim3(256), 0, stream,
                       qT, kT, vv, OPT, lp);
    hipLaunchKernelGGL(merge, dim3(Nn / 64, Cc / 64, Bb), dim3(256), 0, stream,
                       OPT, lp, x, gamma, out);
}